// Round 1
// baseline (1711.979 us; speedup 1.0000x reference)
//
#include <hip/hip_runtime.h>
#include <math.h>

#define L_DIM 8
#define B_DIM 8
#define C_DIM 512
#define D_DIM 4096
#define NPAIR 64          // L*B
#define KSEL 51           // C/10, 0-based index into ascending sort

#define TS 64             // output tile (TS x TS)
#define BK 32             // K-step
#define TSP 68            // padded LDS row (16B-aligned rows, breaks bank conflicts)

// ---------------------------------------------------------------------------
// Kernel 1: G = F * F^T per (l,b) pair, upper-triangle tiles only (+mirror).
// Also extracts diag(G) = ||f_c||^2.
// grid = (36 tile-pairs, pairs-in-chunk), block = 256 (16x16 threads, 4x4 acc)
// ---------------------------------------------------------------------------
__global__ __launch_bounds__(256)
void gram_kernel(const float* __restrict__ F, float* __restrict__ G,
                 float* __restrict__ diag, int pair0) {
    __shared__ float As[BK][TSP];   // transposed: As[k][row]
    __shared__ float Bs[BK][TSP];

    const int p = pair0 + blockIdx.y;

    // map blockIdx.x in [0,36) -> (ti,tj) with ti<=tj over an 8x8 tile grid
    int ti = 0, rem = blockIdx.x;
    while (rem >= (8 - ti)) { rem -= (8 - ti); ++ti; }
    const int tj = ti + rem;

    const float* Fp = F + (size_t)p * C_DIM * D_DIM;
    float* Gp = G + (size_t)blockIdx.y * C_DIM * C_DIM;   // chunk-local

    const int t  = threadIdx.x;
    const int tx = t & 15, ty = t >> 4;
    const int lr = t >> 3;        // 0..31 (load row)
    const int lk = (t & 7) * 4;   // 0,4,...,28 (load k quad)

    const float* aBase = Fp + (size_t)(ti * TS + lr) * D_DIM + lk;
    const float* bBase = Fp + (size_t)(tj * TS + lr) * D_DIM + lk;

    float c[4][4];
#pragma unroll
    for (int i = 0; i < 4; ++i)
#pragma unroll
        for (int j = 0; j < 4; ++j) c[i][j] = 0.f;

    for (int k0 = 0; k0 < D_DIM; k0 += BK) {
        const float4 a0 = *(const float4*)(aBase + k0);
        const float4 a1 = *(const float4*)(aBase + k0 + (size_t)32 * D_DIM);
        const float4 b0 = *(const float4*)(bBase + k0);
        const float4 b1 = *(const float4*)(bBase + k0 + (size_t)32 * D_DIM);
        __syncthreads();   // previous iter's LDS reads done before overwrite
        As[lk+0][lr]    = a0.x; As[lk+1][lr]    = a0.y; As[lk+2][lr]    = a0.z; As[lk+3][lr]    = a0.w;
        As[lk+0][lr+32] = a1.x; As[lk+1][lr+32] = a1.y; As[lk+2][lr+32] = a1.z; As[lk+3][lr+32] = a1.w;
        Bs[lk+0][lr]    = b0.x; Bs[lk+1][lr]    = b0.y; Bs[lk+2][lr]    = b0.z; Bs[lk+3][lr]    = b0.w;
        Bs[lk+0][lr+32] = b1.x; Bs[lk+1][lr+32] = b1.y; Bs[lk+2][lr+32] = b1.z; Bs[lk+3][lr+32] = b1.w;
        __syncthreads();
#pragma unroll
        for (int kk = 0; kk < BK; ++kk) {
            const float4 av = *(const float4*)&As[kk][ty * 4];
            const float4 bv = *(const float4*)&Bs[kk][tx * 4];
            const float ar[4] = {av.x, av.y, av.z, av.w};
            const float br[4] = {bv.x, bv.y, bv.z, bv.w};
#pragma unroll
            for (int i = 0; i < 4; ++i)
#pragma unroll
                for (int j = 0; j < 4; ++j)
                    c[i][j] = fmaf(ar[i], br[j], c[i][j]);
        }
    }

    const int gi0 = ti * TS + ty * 4;
    const int gj0 = tj * TS + tx * 4;
#pragma unroll
    for (int i = 0; i < 4; ++i) {
        float4 w; w.x = c[i][0]; w.y = c[i][1]; w.z = c[i][2]; w.w = c[i][3];
        *(float4*)&Gp[(size_t)(gi0 + i) * C_DIM + gj0] = w;
    }
    if (ti != tj) {
        // mirror into the lower-triangle tile
#pragma unroll
        for (int i = 0; i < 4; ++i)
#pragma unroll
            for (int j = 0; j < 4; ++j)
                Gp[(size_t)(gj0 + j) * C_DIM + gi0 + i] = c[i][j];
    } else if (tx == ty) {
#pragma unroll
        for (int i = 0; i < 4; ++i)
            diag[(size_t)p * C_DIM + gi0 + i] = c[i][i];
    }
}

// ---------------------------------------------------------------------------
// Kernel 2: per (pair,row) build d2[m] = sq[n]+sq[m]-2G[n,m], bitonic-sort 512
// values in LDS, take index KSEL, store sqrt(clip(.,1e-12)).
// grid = (512 rows, pairs-in-chunk), block = 256
// ---------------------------------------------------------------------------
__global__ __launch_bounds__(256)
void select_kernel(const float* __restrict__ G, const float* __restrict__ diag,
                   float* __restrict__ kth, int pair0) {
    __shared__ float s[C_DIM];

    const int row = blockIdx.x;
    const int pl  = blockIdx.y;          // chunk-local pair
    const int p   = pair0 + pl;

    const float* Grow = G + ((size_t)pl * C_DIM + row) * C_DIM;
    const float* dg   = diag + (size_t)p * C_DIM;
    const float sqn   = dg[row];

    for (int m = threadIdx.x; m < C_DIM; m += 256)
        s[m] = sqn + dg[m] - 2.0f * Grow[m];
    __syncthreads();

    // bitonic ascending sort of s[0..511]
    for (int k = 2; k <= C_DIM; k <<= 1) {
        for (int j = k >> 1; j > 0; j >>= 1) {
            for (int i = threadIdx.x; i < C_DIM; i += 256) {
                const int ixj = i ^ j;
                if (ixj > i) {
                    const bool up = (i & k) == 0;
                    const float a = s[i], b = s[ixj];
                    if ((a > b) == up) { s[i] = b; s[ixj] = a; }
                }
            }
            __syncthreads();
        }
    }

    if (threadIdx.x == 0) {
        const float d2 = s[KSEL];
        kth[(size_t)p * C_DIM + row] = sqrtf(fmaxf(d2, 1e-12f));
    }
}

// ---------------------------------------------------------------------------
// Kernel 3: per-layer fp64 sum of the 4096 kth-distances (fixed-order tree ->
// deterministic). grid = 8, block = 256
// ---------------------------------------------------------------------------
__global__ __launch_bounds__(256)
void reduce_kernel(const float* __restrict__ kth, double* __restrict__ hsum) {
    __shared__ double sd[256];
    const int l = blockIdx.x;
    const float* base = kth + (size_t)l * B_DIM * C_DIM;   // 4096 values
    double acc = 0.0;
    for (int i = threadIdx.x; i < B_DIM * C_DIM; i += 256)
        acc += (double)base[i];
    sd[threadIdx.x] = acc;
    __syncthreads();
    for (int sstep = 128; sstep > 0; sstep >>= 1) {
        if (threadIdx.x < sstep) sd[threadIdx.x] += sd[threadIdx.x + sstep];
        __syncthreads();
    }
    if (threadIdx.x == 0) hsum[l] = sd[0];
}

// ---------------------------------------------------------------------------
// Kernel 4: ents = log(S+1); var(d1,ddof=1)+var(d2,ddof=1); single thread.
// ---------------------------------------------------------------------------
__global__ void final_kernel(const double* __restrict__ hsum, float* __restrict__ out) {
    double ents[L_DIM];
    for (int l = 0; l < L_DIM; ++l) ents[l] = log(hsum[l] + 1.0);
    // L=8 -> h = 3
    const double d1[2] = { ents[2] - ents[1], ents[3] - ents[2] };
    const double d2[4] = { ents[4] - ents[3], ents[5] - ents[4],
                           ents[6] - ents[5], ents[7] - ents[6] };
    const double m1 = (d1[0] + d1[1]) * 0.5;
    const double v1 = (d1[0] - m1) * (d1[0] - m1) + (d1[1] - m1) * (d1[1] - m1); // /(2-1)
    double m2 = 0.0;
    for (int i = 0; i < 4; ++i) m2 += d2[i];
    m2 *= 0.25;
    double v2 = 0.0;
    for (int i = 0; i < 4; ++i) v2 += (d2[i] - m2) * (d2[i] - m2);
    v2 /= 3.0;   // ddof=1, n=4
    out[0] = (float)(v1 + v2);
}

// ---------------------------------------------------------------------------
extern "C" void kernel_launch(void* const* d_in, const int* in_sizes, int n_in,
                              void* d_out, int out_size, void* d_ws, size_t ws_size,
                              hipStream_t stream) {
    const float* net = (const float*)d_in[0];
    float* out = (float*)d_out;
    char* ws = (char*)d_ws;

    // workspace layout (all regions fully overwritten every call):
    //   [0,64)                hsum : 8 doubles
    //   [4096, +128KB)        diag : 64*512 f32
    //   [4096+128KB, +128KB)  kth  : 64*512 f32
    //   [266240, ...)         G    : chunk * 1 MB (chunk pairs of 512x512 f32)
    double* hsum = (double*)ws;
    float*  diag = (float*)(ws + 4096);
    float*  kth  = (float*)(ws + 4096 + 131072);
    const size_t gOff = 4096 + 2 * 131072;   // 266240, 256B aligned
    float*  G    = (float*)(ws + gOff);

    const size_t perPair = (size_t)C_DIM * C_DIM * sizeof(float);  // 1 MB
    const size_t avail = ws_size > gOff ? ws_size - gOff : 0;
    int chunk = (int)(avail / perPair);
    if (chunk > NPAIR) chunk = NPAIR;
    if (chunk < 1) chunk = 1;

    for (int p0 = 0; p0 < NPAIR; p0 += chunk) {
        const int np = (NPAIR - p0) < chunk ? (NPAIR - p0) : chunk;
        dim3 gg(36, np);
        gram_kernel<<<gg, dim3(256), 0, stream>>>(net, G, diag, p0);
        dim3 gs(C_DIM, np);
        select_kernel<<<gs, dim3(256), 0, stream>>>(G, diag, kth, p0);
    }
    reduce_kernel<<<dim3(L_DIM), dim3(256), 0, stream>>>(kth, hsum);
    final_kernel<<<dim3(1), dim3(1), 0, stream>>>(hsum, out);
}

// Round 2
// 634.211 us; speedup vs baseline: 2.6994x; 2.6994x over previous
//
#include <hip/hip_runtime.h>
#include <math.h>

#define L_DIM 8
#define B_DIM 8
#define C_DIM 512
#define D_DIM 4096
#define NPAIR 64          // L*B
#define KSEL 51           // C/10, 0-based index into ascending sort

typedef __attribute__((ext_vector_type(8))) short short8;   // 8 bf16 (4 VGPRs)
typedef __attribute__((ext_vector_type(4))) float f32x4;    // MFMA acc

// ---------------------------------------------------------------------------
// split fp32 x -> hi (truncate to bf16) + lo (RNE bf16 of exact residual)
// packs 8 elems into uint4 (hi) + uint4 (lo), bf16 pairs per dword.
// ---------------------------------------------------------------------------
__device__ __forceinline__ void cvt8(float4 f0, float4 f1,
                                     uint4* hi, uint4* lo) {
    const float v[8] = {f0.x, f0.y, f0.z, f0.w, f1.x, f1.y, f1.z, f1.w};
    unsigned int h[8], l[8];
#pragma unroll
    for (int i = 0; i < 8; ++i) {
        const unsigned int u  = __float_as_uint(v[i]);
        const unsigned int hu = u & 0xFFFF0000u;
        const float lf = v[i] - __uint_as_float(hu);     // exact
        const unsigned int lu = __float_as_uint(lf);
        l[i] = (lu + 0x7FFFu + ((lu >> 16) & 1u)) >> 16; // RNE to bf16
        h[i] = u >> 16;                                  // truncate to bf16
    }
    *hi = make_uint4(h[0] | (h[1] << 16), h[2] | (h[3] << 16),
                     h[4] | (h[5] << 16), h[6] | (h[7] << 16));
    *lo = make_uint4(l[0] | (l[1] << 16), l[2] | (l[3] << 16),
                     l[4] | (l[5] << 16), l[6] | (l[7] << 16));
}

// ---------------------------------------------------------------------------
// Kernel 1: G = F * F^T per (l,b) pair via bf16-split MFMA (3 products).
// Upper-triangle 128x128 tiles only (+mirror). Extracts diag(G).
// grid = (10 tile-pairs, pairs-in-chunk), block = 256 (4 waves, 2x2).
// LDS chunk layout is frag-linear: chunk c = mblk*64 + lane holds the 16B an
// MFMA lane needs -> ds_read_b128 at lane*16 (conflict-free); staging writes
// are a bank-optimal permutation.
// ---------------------------------------------------------------------------
__global__ __launch_bounds__(256)
void gram_mfma(const float* __restrict__ F, float* __restrict__ G,
               float* __restrict__ diag, int pair0) {
    __shared__ uint4 sAhi[512], sAlo[512], sBhi[512], sBlo[512];  // 32 KB

    const int p = pair0 + blockIdx.y;
    // blockIdx.x in [0,10) -> (ti,tj), ti<=tj over the 4x4 tile grid
    int ti = 0, rem = blockIdx.x;
    while (rem >= (4 - ti)) { rem -= (4 - ti); ++ti; }
    const int tj = ti + rem;

    const float* Fp = F + (size_t)p * C_DIM * D_DIM;
    float* Gp = G + (size_t)blockIdx.y * C_DIM * C_DIM;   // chunk-local

    const int t = threadIdx.x, lane = t & 63, w = t >> 6;
    const int wr = w >> 1, wc = w & 1;

    // staging: thread t covers rows r0 and r0+64, k-chunk kc*8..+8
    const int r0 = t >> 2, kc = t & 3;
    const int c0 = (r0 >> 4) * 64 + (r0 & 15) + kc * 16;  // frag-linear chunk

    const float* aP = Fp + (size_t)(ti * 128 + r0) * D_DIM + kc * 8;
    const float* bP = Fp + (size_t)(tj * 128 + r0) * D_DIM + kc * 8;
    const size_t rowHop = (size_t)64 * D_DIM;

    f32x4 acc[4][4];
#pragma unroll
    for (int m = 0; m < 4; ++m)
#pragma unroll
        for (int n = 0; n < 4; ++n) acc[m][n] = (f32x4){0.f, 0.f, 0.f, 0.f};

    // prologue: load k=0 slabs into registers
    float4 A00 = *(const float4*)(aP),          A01 = *(const float4*)(aP + 4);
    float4 A10 = *(const float4*)(aP + rowHop), A11 = *(const float4*)(aP + rowHop + 4);
    float4 B00 = *(const float4*)(bP),          B01 = *(const float4*)(bP + 4);
    float4 B10 = *(const float4*)(bP + rowHop), B11 = *(const float4*)(bP + rowHop + 4);

    for (int k0 = 0; k0 < D_DIM; k0 += 32) {
        __syncthreads();     // prior iteration's frag reads are consumed
        uint4 h, l;
        cvt8(A00, A01, &h, &l); sAhi[c0]       = h; sAlo[c0]       = l;
        cvt8(A10, A11, &h, &l); sAhi[c0 + 256] = h; sAlo[c0 + 256] = l;
        cvt8(B00, B01, &h, &l); sBhi[c0]       = h; sBlo[c0]       = l;
        cvt8(B10, B11, &h, &l); sBhi[c0 + 256] = h; sBlo[c0 + 256] = l;
        __syncthreads();

        if (k0 + 32 < D_DIM) {   // prefetch next K-slab; lands during MFMA
            const float* ap = aP + k0 + 32;
            const float* bp = bP + k0 + 32;
            A00 = *(const float4*)(ap);          A01 = *(const float4*)(ap + 4);
            A10 = *(const float4*)(ap + rowHop); A11 = *(const float4*)(ap + rowHop + 4);
            B00 = *(const float4*)(bp);          B01 = *(const float4*)(bp + 4);
            B10 = *(const float4*)(bp + rowHop); B11 = *(const float4*)(bp + rowHop + 4);
        }

        short8 ah[4], al[4], bh[4], bl[4];
#pragma unroll
        for (int m = 0; m < 4; ++m) {
            const int ci = (wr * 4 + m) * 64 + lane;
            ah[m] = *(const short8*)&sAhi[ci];
            al[m] = *(const short8*)&sAlo[ci];
        }
#pragma unroll
        for (int n = 0; n < 4; ++n) {
            const int ci = (wc * 4 + n) * 64 + lane;
            bh[n] = *(const short8*)&sBhi[ci];
            bl[n] = *(const short8*)&sBlo[ci];
        }
#pragma unroll
        for (int m = 0; m < 4; ++m)
#pragma unroll
            for (int n = 0; n < 4; ++n) {
                acc[m][n] = __builtin_amdgcn_mfma_f32_16x16x32_bf16(ah[m], bh[n], acc[m][n], 0, 0, 0);
                acc[m][n] = __builtin_amdgcn_mfma_f32_16x16x32_bf16(ah[m], bl[n], acc[m][n], 0, 0, 0);
                acc[m][n] = __builtin_amdgcn_mfma_f32_16x16x32_bf16(al[m], bh[n], acc[m][n], 0, 0, 0);
            }
    }

    // epilogue: C/D map col=lane&15, row=(lane>>4)*4+reg  [m89-verified]
    const int gr0 = ti * 128 + wr * 64;
    const int gc0 = tj * 128 + wc * 64;
    const int fr = (lane >> 4) * 4;
    const int fc = lane & 15;
#pragma unroll
    for (int m = 0; m < 4; ++m)
#pragma unroll
        for (int n = 0; n < 4; ++n) {
            const int rr = gr0 + m * 16 + fr;
            const int cc = gc0 + n * 16 + fc;
#pragma unroll
            for (int j = 0; j < 4; ++j)
                Gp[(size_t)(rr + j) * C_DIM + cc] = acc[m][n][j];
        }
    if (ti != tj) {
        // mirror into the lower-triangle tile (G symmetric)
#pragma unroll
        for (int m = 0; m < 4; ++m)
#pragma unroll
            for (int n = 0; n < 4; ++n) {
                const int rr = gr0 + m * 16 + fr;
                const int cc = gc0 + n * 16 + fc;
#pragma unroll
                for (int j = 0; j < 4; ++j)
                    Gp[(size_t)cc * C_DIM + rr + j] = acc[m][n][j];
            }
    } else if (wr == wc && ((fc >> 2) == (lane >> 4))) {
        // diagonal extraction: row==col within frag m==n
        const int j = fc & 3;
#pragma unroll
        for (int m = 0; m < 4; ++m)
            diag[(size_t)p * C_DIM + gr0 + m * 16 + fc] = acc[m][m][j];
    }
}

// ---------------------------------------------------------------------------
// Kernel 2: per (pair,row) build d2[m] = sq[n]+sq[m]-2G[n,m], bitonic-sort 512
// values in LDS, take index KSEL, store sqrt(clip(.,1e-12)).
// ---------------------------------------------------------------------------
__global__ __launch_bounds__(256)
void select_kernel(const float* __restrict__ G, const float* __restrict__ diag,
                   float* __restrict__ kth, int pair0) {
    __shared__ float s[C_DIM];

    const int row = blockIdx.x;
    const int pl  = blockIdx.y;
    const int p   = pair0 + pl;

    const float* Grow = G + ((size_t)pl * C_DIM + row) * C_DIM;
    const float* dg   = diag + (size_t)p * C_DIM;
    const float sqn   = dg[row];

    for (int m = threadIdx.x; m < C_DIM; m += 256)
        s[m] = sqn + dg[m] - 2.0f * Grow[m];
    __syncthreads();

    for (int k = 2; k <= C_DIM; k <<= 1) {
        for (int j = k >> 1; j > 0; j >>= 1) {
            for (int i = threadIdx.x; i < C_DIM; i += 256) {
                const int ixj = i ^ j;
                if (ixj > i) {
                    const bool up = (i & k) == 0;
                    const float a = s[i], b = s[ixj];
                    if ((a > b) == up) { s[i] = b; s[ixj] = a; }
                }
            }
            __syncthreads();
        }
    }

    if (threadIdx.x == 0) {
        const float d2 = s[KSEL];
        kth[(size_t)p * C_DIM + row] = sqrtf(fmaxf(d2, 1e-12f));
    }
}

// ---------------------------------------------------------------------------
// Kernel 3: per-layer fp64 fixed-order sum of 4096 kth-distances.
// ---------------------------------------------------------------------------
__global__ __launch_bounds__(256)
void reduce_kernel(const float* __restrict__ kth, double* __restrict__ hsum) {
    __shared__ double sd[256];
    const int l = blockIdx.x;
    const float* base = kth + (size_t)l * B_DIM * C_DIM;
    double acc = 0.0;
    for (int i = threadIdx.x; i < B_DIM * C_DIM; i += 256)
        acc += (double)base[i];
    sd[threadIdx.x] = acc;
    __syncthreads();
    for (int sstep = 128; sstep > 0; sstep >>= 1) {
        if (threadIdx.x < sstep) sd[threadIdx.x] += sd[threadIdx.x + sstep];
        __syncthreads();
    }
    if (threadIdx.x == 0) hsum[l] = sd[0];
}

// ---------------------------------------------------------------------------
// Kernel 4: ents = log(S+1); var(d1,ddof=1)+var(d2,ddof=1).
// ---------------------------------------------------------------------------
__global__ void final_kernel(const double* __restrict__ hsum, float* __restrict__ out) {
    double ents[L_DIM];
    for (int l = 0; l < L_DIM; ++l) ents[l] = log(hsum[l] + 1.0);
    const double d1[2] = { ents[2] - ents[1], ents[3] - ents[2] };
    const double d2[4] = { ents[4] - ents[3], ents[5] - ents[4],
                           ents[6] - ents[5], ents[7] - ents[6] };
    const double m1 = (d1[0] + d1[1]) * 0.5;
    const double v1 = (d1[0] - m1) * (d1[0] - m1) + (d1[1] - m1) * (d1[1] - m1);
    double m2 = 0.0;
    for (int i = 0; i < 4; ++i) m2 += d2[i];
    m2 *= 0.25;
    double v2 = 0.0;
    for (int i = 0; i < 4; ++i) v2 += (d2[i] - m2) * (d2[i] - m2);
    v2 /= 3.0;
    out[0] = (float)(v1 + v2);
}

// ---------------------------------------------------------------------------
extern "C" void kernel_launch(void* const* d_in, const int* in_sizes, int n_in,
                              void* d_out, int out_size, void* d_ws, size_t ws_size,
                              hipStream_t stream) {
    const float* net = (const float*)d_in[0];
    float* out = (float*)d_out;
    char* ws = (char*)d_ws;

    double* hsum = (double*)ws;
    float*  diag = (float*)(ws + 4096);
    float*  kth  = (float*)(ws + 4096 + 131072);
    const size_t gOff = 4096 + 2 * 131072;
    float*  G    = (float*)(ws + gOff);

    const size_t perPair = (size_t)C_DIM * C_DIM * sizeof(float);
    const size_t avail = ws_size > gOff ? ws_size - gOff : 0;
    int chunk = (int)(avail / perPair);
    if (chunk > NPAIR) chunk = NPAIR;
    if (chunk < 1) chunk = 1;

    for (int p0 = 0; p0 < NPAIR; p0 += chunk) {
        const int np = (NPAIR - p0) < chunk ? (NPAIR - p0) : chunk;
        gram_mfma<<<dim3(10, np), dim3(256), 0, stream>>>(net, G, diag, p0);
        select_kernel<<<dim3(C_DIM, np), dim3(256), 0, stream>>>(G, diag, kth, p0);
    }
    reduce_kernel<<<dim3(L_DIM), dim3(256), 0, stream>>>(kth, hsum);
    final_kernel<<<dim3(1), dim3(1), 0, stream>>>(hsum, out);
}

// Round 3
// 278.025 us; speedup vs baseline: 6.1576x; 2.2811x over previous
//
#include <hip/hip_runtime.h>
#include <math.h>

#define L_DIM 8
#define B_DIM 8
#define C_DIM 512
#define D_DIM 4096
#define NPAIR 64          // L*B
#define KSEL_CNT 52       // 52nd smallest = 0-based sorted index 51 (k = C/10)

typedef __attribute__((ext_vector_type(8))) _Float16 half8;  // MFMA f16 operand
typedef __attribute__((ext_vector_type(4))) float f32x4;     // MFMA acc

// chunk-index bank swizzle: mixes kc (bits[5:4]) into bank bits [2:1].
// writer groups (rows{2r,2r+1} x kc0..3) and reader groups (8 consecutive
// rows, kc fixed) both hit 8 distinct bank-quads -> conflict-free b128.
__device__ __forceinline__ int swz(int c) { return c ^ (((c >> 4) & 3) << 1); }

__device__ __forceinline__ uint4 cvth8(float4 f0, float4 f1) {
    half8 h;
    h[0] = (_Float16)f0.x; h[1] = (_Float16)f0.y;
    h[2] = (_Float16)f0.z; h[3] = (_Float16)f0.w;
    h[4] = (_Float16)f1.x; h[5] = (_Float16)f1.y;
    h[6] = (_Float16)f1.z; h[7] = (_Float16)f1.w;
    return __builtin_bit_cast(uint4, h);
}

// ---------------------------------------------------------------------------
// Kernel 1: G = F * F^T per (l,b) pair, fp16 hi*hi MFMA (single product).
// 128x128 upper-triangle tiles (+mirror), diag extraction.
// grid = 10*np flat; blocks of one pair are clustered mod 8 -> same XCD L2.
// ---------------------------------------------------------------------------
__global__ __launch_bounds__(256)
void gram_mfma(const float* __restrict__ F, float* __restrict__ G,
               float* __restrict__ diag, int pair0, int np) {
    __shared__ uint4 sA[512], sB[512];    // 16 KB total

    int bidx = blockIdx.x;
    int pl, tileid;
    if ((np & 7) == 0) {          // XCD clustering: pair pl -> blocks == pl (mod 8)
        const int r = bidx & 7, q = bidx >> 3;
        pl = r + 8 * (q / 10);
        tileid = q % 10;
    } else {
        pl = bidx / 10;
        tileid = bidx % 10;
    }
    const int p = pair0 + pl;

    int ti = 0, rem = tileid;     // (ti,tj), ti<=tj over 4x4 tile grid
    while (rem >= (4 - ti)) { rem -= (4 - ti); ++ti; }
    const int tj = ti + rem;

    const float* Fp = F + (size_t)p * C_DIM * D_DIM;
    float* Gp = G + (size_t)pl * C_DIM * C_DIM;

    const int t = threadIdx.x, lane = t & 63, w = t >> 6;
    const int wr = w >> 1, wc = w & 1;

    // staging: thread t covers rows r0 and r0+64, k-chunk kc*8..+8
    const int r0 = t >> 2, kc = t & 3;
    const int cA = (r0 >> 4) * 64 + (r0 & 15) + kc * 16;   // frag-linear chunk
    const int st0 = swz(cA), st1 = swz(cA + 256);

    const float* aP = Fp + (size_t)(ti * 128 + r0) * D_DIM + kc * 8;
    const float* bP = Fp + (size_t)(tj * 128 + r0) * D_DIM + kc * 8;
    const size_t rowHop = (size_t)64 * D_DIM;

    f32x4 acc[4][4];
#pragma unroll
    for (int m = 0; m < 4; ++m)
#pragma unroll
        for (int n = 0; n < 4; ++n) acc[m][n] = (f32x4){0.f, 0.f, 0.f, 0.f};

    // frag read addresses (loop-invariant)
    int rdA[4], rdB[4];
#pragma unroll
    for (int m = 0; m < 4; ++m) rdA[m] = swz((wr * 4 + m) * 64 + lane);
#pragma unroll
    for (int n = 0; n < 4; ++n) rdB[n] = swz((wc * 4 + n) * 64 + lane);

    // prologue: load + convert slab 0
    float4 A00 = *(const float4*)(aP),          A01 = *(const float4*)(aP + 4);
    float4 A10 = *(const float4*)(aP + rowHop), A11 = *(const float4*)(aP + rowHop + 4);
    float4 B00 = *(const float4*)(bP),          B01 = *(const float4*)(bP + 4);
    float4 B10 = *(const float4*)(bP + rowHop), B11 = *(const float4*)(bP + rowHop + 4);
    uint4 cA0 = cvth8(A00, A01), cA1 = cvth8(A10, A11);
    uint4 cB0 = cvth8(B00, B01), cB1 = cvth8(B10, B11);

    for (int k0 = 0; k0 < D_DIM; k0 += 32) {
        __syncthreads();          // prior slab's frag reads consumed
        sA[st0] = cA0; sA[st1] = cA1;
        sB[st0] = cB0; sB[st1] = cB1;
        __syncthreads();

        if (k0 + 32 < D_DIM) {    // prefetch next slab; lands during MFMA
            const float* ap = aP + k0 + 32;
            const float* bp = bP + k0 + 32;
            A00 = *(const float4*)(ap);          A01 = *(const float4*)(ap + 4);
            A10 = *(const float4*)(ap + rowHop); A11 = *(const float4*)(ap + rowHop + 4);
            B00 = *(const float4*)(bp);          B01 = *(const float4*)(bp + 4);
            B10 = *(const float4*)(bp + rowHop); B11 = *(const float4*)(bp + rowHop + 4);
        }

        half8 ah[4], bh[4];
#pragma unroll
        for (int m = 0; m < 4; ++m) ah[m] = __builtin_bit_cast(half8, sA[rdA[m]]);
#pragma unroll
        for (int n = 0; n < 4; ++n) bh[n] = __builtin_bit_cast(half8, sB[rdB[n]]);
#pragma unroll
        for (int m = 0; m < 4; ++m)
#pragma unroll
            for (int n = 0; n < 4; ++n)
                acc[m][n] = __builtin_amdgcn_mfma_f32_16x16x32_f16(ah[m], bh[n], acc[m][n], 0, 0, 0);

        cA0 = cvth8(A00, A01); cA1 = cvth8(A10, A11);
        cB0 = cvth8(B00, B01); cB1 = cvth8(B10, B11);
    }

    // epilogue: C/D map col=lane&15, row=(lane>>4)*4+reg
    const int gr0 = ti * 128 + wr * 64;
    const int gc0 = tj * 128 + wc * 64;
    const int fr = (lane >> 4) * 4;
    const int fc = lane & 15;
#pragma unroll
    for (int m = 0; m < 4; ++m)
#pragma unroll
        for (int n = 0; n < 4; ++n) {
            const int rr = gr0 + m * 16 + fr;
            const int cc = gc0 + n * 16 + fc;
#pragma unroll
            for (int j = 0; j < 4; ++j)
                Gp[(size_t)(rr + j) * C_DIM + cc] = acc[m][n][j];
        }
    if (ti != tj) {
#pragma unroll
        for (int m = 0; m < 4; ++m)
#pragma unroll
            for (int n = 0; n < 4; ++n) {
                const int rr = gr0 + m * 16 + fr;
                const int cc = gc0 + n * 16 + fc;
#pragma unroll
                for (int j = 0; j < 4; ++j)
                    Gp[(size_t)cc * C_DIM + rr + j] = acc[m][n][j];
            }
    } else if (wr == wc && ((fc >> 2) == (lane >> 4))) {
        const int j = fc & 3;
#pragma unroll
        for (int m = 0; m < 4; ++m)
            diag[(size_t)p * C_DIM + gr0 + m * 16 + fc] = acc[m][m][j];
    }
}

// ---------------------------------------------------------------------------
// Kernel 2: one wave per row. d2[m] = sq[n]+sq[m]-2G[n,m] held in 8 regs/lane;
// bit-pattern bisection finds the 52nd smallest exactly (attained value).
// grid = (C/4, np), block = 256 (4 waves).
// ---------------------------------------------------------------------------
__global__ __launch_bounds__(256)
void select_kernel(const float* __restrict__ G, const float* __restrict__ diag,
                   float* __restrict__ kth, int pair0) {
    const int w = threadIdx.x >> 6, lane = threadIdx.x & 63;
    const int row = blockIdx.x * 4 + w;
    const int pl  = blockIdx.y;
    const int p   = pair0 + pl;

    const float* Grow = G + ((size_t)pl * C_DIM + row) * C_DIM;
    const float* dg   = diag + (size_t)p * C_DIM;
    const float  sqn  = dg[row];

    const float4 g0 = *(const float4*)(Grow + lane * 8);
    const float4 g1 = *(const float4*)(Grow + lane * 8 + 4);
    const float4 d0 = *(const float4*)(dg + lane * 8);
    const float4 d1 = *(const float4*)(dg + lane * 8 + 4);

    float v[8];
    v[0] = fmaxf(sqn + d0.x - 2.f * g0.x, 0.f);
    v[1] = fmaxf(sqn + d0.y - 2.f * g0.y, 0.f);
    v[2] = fmaxf(sqn + d0.z - 2.f * g0.z, 0.f);
    v[3] = fmaxf(sqn + d0.w - 2.f * g0.w, 0.f);
    v[4] = fmaxf(sqn + d1.x - 2.f * g1.x, 0.f);
    v[5] = fmaxf(sqn + d1.y - 2.f * g1.y, 0.f);
    v[6] = fmaxf(sqn + d1.z - 2.f * g1.z, 0.f);
    v[7] = fmaxf(sqn + d1.w - 2.f * g1.w, 0.f);

    // smallest uint pattern P with count(v <= float(P)) >= 52  ==  sorted[51]
    unsigned lo = 0u, hi = 0x47800000u;   // 65536.0f >> max d2 (~9e3)
    while (lo < hi) {
        const unsigned mid = (lo + hi) >> 1;
        const float piv = __uint_as_float(mid);
        int c = 0;
#pragma unroll
        for (int i = 0; i < 8; ++i) c += (v[i] <= piv) ? 1 : 0;
#pragma unroll
        for (int off = 32; off > 0; off >>= 1) c += __shfl_xor(c, off);
        if (c >= KSEL_CNT) hi = mid; else lo = mid + 1;
    }
    if (lane == 0)
        kth[(size_t)p * C_DIM + row] = sqrtf(fmaxf(__uint_as_float(lo), 1e-12f));
}

// ---------------------------------------------------------------------------
// Kernel 3: per-layer fp64 fixed-order sum of 4096 kth-distances.
// ---------------------------------------------------------------------------
__global__ __launch_bounds__(256)
void reduce_kernel(const float* __restrict__ kth, double* __restrict__ hsum) {
    __shared__ double sd[256];
    const int l = blockIdx.x;
    const float* base = kth + (size_t)l * B_DIM * C_DIM;
    double acc = 0.0;
    for (int i = threadIdx.x; i < B_DIM * C_DIM; i += 256)
        acc += (double)base[i];
    sd[threadIdx.x] = acc;
    __syncthreads();
    for (int sstep = 128; sstep > 0; sstep >>= 1) {
        if (threadIdx.x < sstep) sd[threadIdx.x] += sd[threadIdx.x + sstep];
        __syncthreads();
    }
    if (threadIdx.x == 0) hsum[l] = sd[0];
}

// ---------------------------------------------------------------------------
// Kernel 4: ents = log(S+1); var(d1,ddof=1)+var(d2,ddof=1).
// ---------------------------------------------------------------------------
__global__ void final_kernel(const double* __restrict__ hsum, float* __restrict__ out) {
    double ents[L_DIM];
    for (int l = 0; l < L_DIM; ++l) ents[l] = log(hsum[l] + 1.0);
    const double d1[2] = { ents[2] - ents[1], ents[3] - ents[2] };
    const double d2[4] = { ents[4] - ents[3], ents[5] - ents[4],
                           ents[6] - ents[5], ents[7] - ents[6] };
    const double m1 = (d1[0] + d1[1]) * 0.5;
    const double v1 = (d1[0] - m1) * (d1[0] - m1) + (d1[1] - m1) * (d1[1] - m1);
    double m2 = 0.0;
    for (int i = 0; i < 4; ++i) m2 += d2[i];
    m2 *= 0.25;
    double v2 = 0.0;
    for (int i = 0; i < 4; ++i) v2 += (d2[i] - m2) * (d2[i] - m2);
    v2 /= 3.0;
    out[0] = (float)(v1 + v2);
}

// ---------------------------------------------------------------------------
extern "C" void kernel_launch(void* const* d_in, const int* in_sizes, int n_in,
                              void* d_out, int out_size, void* d_ws, size_t ws_size,
                              hipStream_t stream) {
    const float* net = (const float*)d_in[0];
    float* out = (float*)d_out;
    char* ws = (char*)d_ws;

    double* hsum = (double*)ws;
    float*  diag = (float*)(ws + 4096);
    float*  kth  = (float*)(ws + 4096 + 131072);
    const size_t gOff = 4096 + 2 * 131072;
    float*  G    = (float*)(ws + gOff);

    const size_t perPair = (size_t)C_DIM * C_DIM * sizeof(float);
    const size_t avail = ws_size > gOff ? ws_size - gOff : 0;
    int chunk = (int)(avail / perPair);
    if (chunk > NPAIR) chunk = NPAIR;
    if (chunk < 1) chunk = 1;

    for (int p0 = 0; p0 < NPAIR; p0 += chunk) {
        const int np = (NPAIR - p0) < chunk ? (NPAIR - p0) : chunk;
        gram_mfma<<<dim3(10 * np), dim3(256), 0, stream>>>(net, G, diag, p0, np);
        select_kernel<<<dim3(C_DIM / 4, np), dim3(256), 0, stream>>>(G, diag, kth, p0);
    }
    reduce_kernel<<<dim3(L_DIM), dim3(256), 0, stream>>>(kth, hsum);
    final_kernel<<<dim3(1), dim3(1), 0, stream>>>(hsum, out);
}